// Round 9
// baseline (39.486 us; speedup 1.0000x reference)
//
#include <hip/hip_runtime.h>
#include <math.h>

typedef short  bf16x8 __attribute__((ext_vector_type(8)));
typedef float  f32x16 __attribute__((ext_vector_type(16)));

constexpr int BATCH = 4, NPTS = 8192;
constexpr int CLOUD = BATCH * NPTS;     // 32768 points per cloud

__device__ inline unsigned bf16_rne(float x) {
    unsigned u = __float_as_uint(x);
    return (u + 0x7FFFu + ((u >> 16) & 1u)) >> 16;
}
__device__ inline float bf16_val(unsigned h) {
    return __uint_as_float(h << 16);
}

// K=16 bf16 factorization of d^2 = r1 + r2 - 2 x.y (proven exact-enough:
// absmax 0.0 in R5-R8). A[n]: [hx,lx,hx, hy,ly,hy, hz,lz,hz, 1,1,1, r0,r1,r2, 0]
//                       B[m]: [ax,ax,bx, ay,ay,by, az,az,bz, s0,s1,s2, 1,1,1, 0]
// (a*/b* = hi/lo of -2*coord; r*/s* = 3-way bf16 split of |p|^2)
struct Pack2 { uint4 s0, s1; };

__device__ inline Pack2 packA(float x, float y, float z) {
    const unsigned one = 0x3F80u;
    const float r = x*x + y*y + z*z;
    const unsigned r0 = bf16_rne(r);
    const float rm1 = r - bf16_val(r0);
    const unsigned r1 = bf16_rne(rm1);
    const unsigned r2 = bf16_rne(rm1 - bf16_val(r1));
    const unsigned hx = bf16_rne(x), hy = bf16_rne(y), hz = bf16_rne(z);
    const unsigned lx = bf16_rne(x - bf16_val(hx));
    const unsigned ly = bf16_rne(y - bf16_val(hy));
    const unsigned lz = bf16_rne(z - bf16_val(hz));
    Pack2 P;
    P.s0.x = hx | (lx << 16);  P.s0.y = hx | (hy << 16);
    P.s0.z = ly | (hy << 16);  P.s0.w = hz | (lz << 16);
    P.s1.x = hz | (one << 16); P.s1.y = one | (one << 16);
    P.s1.z = r0 | (r1 << 16);  P.s1.w = r2;
    return P;
}
__device__ inline Pack2 packB(float x, float y, float z) {
    const unsigned one = 0x3F80u;
    const float r = x*x + y*y + z*z;
    const unsigned r0 = bf16_rne(r);
    const float rm1 = r - bf16_val(r0);
    const unsigned r1 = bf16_rne(rm1);
    const unsigned r2 = bf16_rne(rm1 - bf16_val(r1));
    const float tx = -2.f*x, ty = -2.f*y, tz = -2.f*z;
    const unsigned ax = bf16_rne(tx), ay = bf16_rne(ty), az = bf16_rne(tz);
    const unsigned bx = bf16_rne(tx - bf16_val(ax));
    const unsigned by = bf16_rne(ty - bf16_val(ay));
    const unsigned bz = bf16_rne(tz - bf16_val(az));
    Pack2 P;
    P.s0.x = ax | (ax << 16);  P.s0.y = bx | (ay << 16);
    P.s0.z = ay | (by << 16);  P.s0.w = az | (az << 16);
    P.s1.x = bz | (r0 << 16);  P.s1.y = r1 | (r2 << 16);
    P.s1.z = one | (one << 16);P.s1.w = one;
    return P;
}

// ---------------- fused pack+gemm+min: block = 4 waves x 64 rows, shared
// 1024-col B chunk packed into LDS on the fly from raw xyz.
// wid bits: dir(1) | b(2) | cc(3) | rg(7). Writes per-plane row-min partials.
__global__ __launch_bounds__(256) void cd_main(
    const float* __restrict__ x1, const float* __restrict__ x2,
    float* __restrict__ partial,
    unsigned long long* __restrict__ total, unsigned int* __restrict__ counter) {

    __shared__ uint4 Blds[2048];          // 32 KB; reused as epilogue transpose

    const int tid = threadIdx.x;
    const int wv  = tid >> 6;
    const int l   = tid & 63;
    const int lane31 = l & 31, half = l >> 5;

    if (blockIdx.x == 0 && tid == 0) { *total = 0ULL; *counter = 0u; }

    const int wid = blockIdx.x * 4 + wv;       // 0..8191
    const int dir = wid >> 12;
    const int b   = (wid >> 10) & 3;
    const int cc  = (wid >> 7) & 7;
    const int rg  = wid & 127;                 // 64-row groups

    // ---- stage B chunk: 4 points/thread from raw xyz, pack, fragment-major
    {
        const float* oth = dir ? x1 : x2;      // block-uniform (wid high bits)
        const int othBase = b * NPTS + cc * 1024;
        const float4* src =
            reinterpret_cast<const float4*>(oth + (size_t)othBase * 3) + tid * 3;
        float4 A = src[0], Q = src[1], C = src[2];
        const float px[4] = {A.x, A.w, Q.z, C.y};
        const float py[4] = {A.y, Q.x, Q.w, C.z};
        const float pz[4] = {A.z, Q.y, C.x, C.w};
#pragma unroll
        for (int j = 0; j < 4; ++j) {
            Pack2 P = packB(px[j], py[j], pz[j]);
            const int pt = 4 * tid + j, g = pt >> 5, w = pt & 31;
            Blds[g * 64 + w]      = P.s0;
            Blds[g * 64 + 32 + w] = P.s1;
        }
    }

    // ---- A fragments (2 x 32 rows): pack own rows on the fly
    bf16x8 afr0, afr1;
    {
        const float* own = dir ? x2 : x1;
        const int r0i = (b * NPTS + rg * 64 + lane31) * 3;
        Pack2 PA = packA(own[r0i], own[r0i + 1], own[r0i + 2]);
        Pack2 PB = packA(own[r0i + 96], own[r0i + 97], own[r0i + 98]); // +32 rows
        uint4 s0 = half ? PA.s1 : PA.s0;
        uint4 s1 = half ? PB.s1 : PB.s0;
        __builtin_memcpy(&afr0, &s0, 16);
        __builtin_memcpy(&afr1, &s1, 16);
    }

    f32x16 zc;
#pragma unroll
    for (int i = 0; i < 16; ++i) zc[i] = 0.0f;

    float racc[2][16];
#pragma unroll
    for (int f = 0; f < 2; ++f)
#pragma unroll
        for (int r = 0; r < 16; ++r) racc[f][r] = INFINITY;

    __syncthreads();

    // ---- sweep 16 col-pairs: 2 ds_read_b128 + 4 MFMA (2+2) + 32 v_min3
#pragma unroll 4
    for (int p = 0; p < 16; ++p) {
        bf16x8 ba, bb;
        uint4 ua = Blds[(2*p + 0) * 64 + l];
        uint4 ub = Blds[(2*p + 1) * 64 + l];
        __builtin_memcpy(&ba, &ua, 16);
        __builtin_memcpy(&bb, &ub, 16);
        f32x16 c0 = __builtin_amdgcn_mfma_f32_32x32x16_bf16(afr0, ba, zc, 0, 0, 0);
        f32x16 c1 = __builtin_amdgcn_mfma_f32_32x32x16_bf16(afr0, bb, zc, 0, 0, 0);
#pragma unroll
        for (int r = 0; r < 16; ++r)
            racc[0][r] = fminf(fminf(c0[r], c1[r]), racc[0][r]);   // v_min3
        f32x16 c2 = __builtin_amdgcn_mfma_f32_32x32x16_bf16(afr1, ba, zc, 0, 0, 0);
        f32x16 c3 = __builtin_amdgcn_mfma_f32_32x32x16_bf16(afr1, bb, zc, 0, 0, 0);
#pragma unroll
        for (int r = 0; r < 16; ++r)
            racc[1][r] = fminf(fminf(c2[r], c3[r]), racc[1][r]);
    }

    __syncthreads();   // B-chunk dead; reuse LDS for per-wave transpose

    float* lbuf = reinterpret_cast<float*>(Blds) + wv * (32 * 33);
    const int pBase = (dir * 8 + cc) * CLOUD + b * NPTS + rg * 64;
#pragma unroll
    for (int f = 0; f < 2; ++f) {
#pragma unroll
        for (int r = 0; r < 16; ++r) {
            const int rl = (r & 3) + 8 * (r >> 2) + 4 * half;  // C/D row map
            lbuf[rl * 33 + lane31] = racc[f][r];
        }
        const int row = l >> 1;
        float m = INFINITY;
#pragma unroll
        for (int i = 0; i < 16; ++i)
            m = fminf(m, lbuf[row * 33 + (l & 1) * 16 + i]);
        m = fminf(m, __shfl_xor(m, 1, 64));
        if ((l & 1) == 0)
            partial[pBase + f * 32 + row] = fmaxf(m, 0.0f);
    }
}

// ---------------- reduce: min over 8 planes per row, deterministic
// fixed-point (2^30) u64 atomic sum, last-wave finalizes out[0].
__global__ __launch_bounds__(256) void cd_reduce(
    const float* __restrict__ partial,
    unsigned long long* __restrict__ total, unsigned int* __restrict__ counter,
    float* __restrict__ out) {
    const int tid = threadIdx.x, bid = blockIdx.x;   // 32 blocks x 256
    double s = 0.0;
#pragma unroll
    for (int k = 0; k < 8; ++k) {
        const int R  = bid * 2048 + k * 256 + tid;   // 0..65535
        const int d  = R >> 15, rr = R & 32767;
        const float* pp = partial + (size_t)(d * 8) * CLOUD + rr;
        float m = pp[0];
#pragma unroll
        for (int c = 1; c < 8; ++c) m = fminf(m, pp[(size_t)c * CLOUD]);
        s += (double)m;
    }
#pragma unroll
    for (int off = 32; off > 0; off >>= 1) s += __shfl_down(s, off, 64);
    if ((tid & 63) == 0) {
        const unsigned long long q =
            (unsigned long long)(s * 1073741824.0 + 0.5);
        atomicAdd(total, q);
        __threadfence();
        const unsigned old = atomicAdd(counter, 1u);
        if (old == 127u) {                 // 32 blocks * 4 waves
            __threadfence();
            const unsigned long long t = atomicAdd(total, 0ULL);
            out[0] = (float)((double)t * (1.0 / 1073741824.0) / (double)CLOUD);
        }
    }
}

extern "C" void kernel_launch(void* const* d_in, const int* in_sizes, int n_in,
                              void* d_out, int out_size, void* d_ws, size_t ws_size,
                              hipStream_t stream) {
    const float* xyz1 = (const float*)d_in[0];
    const float* xyz2 = (const float*)d_in[1];
    float* partial = (float*)d_ws;                                   // 2 MB
    unsigned long long* total =
        (unsigned long long*)((char*)d_ws + 16u * CLOUD * 4u);
    unsigned int* counter = (unsigned int*)(total + 1);
    float* out = (float*)d_out;

    cd_main<<<2048, 256, 0, stream>>>(xyz1, xyz2, partial, total, counter);
    cd_reduce<<<32, 256, 0, stream>>>(partial, total, counter, out);
}